// Round 7
// baseline (973.390 us; speedup 1.0000x reference)
//
#include <hip/hip_runtime.h>
#include <math.h>

#define Lc 4
#define Bc 4
#define Tc 1024
#define TCc 1024
#define T1c 2048
#define Dc 384
#define DKc 256
#define FFc 1536
#define TTc 0.1f
#define EPSc 1e-5f
#define QUc 640   // [qk(256); unk(384)] fused projection width

typedef unsigned short u16;
typedef __attribute__((ext_vector_type(8))) __bf16 bf16x8;
typedef __attribute__((ext_vector_type(8))) _Float16 f16x8;
typedef __attribute__((ext_vector_type(4))) float f32x4;

__device__ inline u16 f2bf(float f) {
  union { float f; unsigned u; } x; x.f = f;
  unsigned r = x.u + 0x7fffu + ((x.u >> 16) & 1u);
  return (u16)(r >> 16);
}
__device__ inline float bf2f(u16 v) {
  union { unsigned u; float f; } x; x.u = (unsigned)v << 16; return x.f;
}

// ---------------- multi-tensor fp32 -> bf16 convert (float4/ushort4) ----------------
struct CDesc { const float* src; u16* dst; long n4; };
struct CPack { CDesc d[16]; long tot4; int nd; };

__global__ void cvt_multi(CPack P) {
  long i = (long)blockIdx.x * 256 + threadIdx.x;
  const long st = (long)gridDim.x * 256;
  for (; i < P.tot4; i += st) {
    long r = i; int g = 0;
    while (g < P.nd - 1 && r >= P.d[g].n4) { r -= P.d[g].n4; ++g; }
    float4 v = ((const float4*)P.d[g].src)[r];
    ushort4 o;
    o.x = f2bf(v.x); o.y = f2bf(v.y); o.z = f2bf(v.z); o.w = f2bf(v.w);
    ((ushort4*)P.d[g].dst)[r] = o;
  }
}

// bqu[l][0..256) = bq[l].Wk[l] (via WkT rows), bqu[l][256..640) = bun[l]
__global__ void make_bias(const float* __restrict__ bq, const float* __restrict__ bun,
                          const u16* __restrict__ wkT, float* __restrict__ bqu) {
  const int l = blockIdx.x, t = threadIdx.x;
  if (t < DKc) {
    const u16* w = wkT + ((long)l * DKc + t) * Dc;
    const float* b = bq + l * Dc;
    float s = 0.f;
    for (int e = 0; e < Dc; ++e) s += b[e] * bf2f(w[e]);
    bqu[l * QUc + t] = s;
  } else {
    bqu[l * QUc + t] = bun[l * Dc + (t - DKc)];
  }
}

// ------- src[z] (R,C) fp32 -> dst[z] (C,R) bf16, 64x64 tiles -------
// grid (C/64, R/64, batch)
__global__ __launch_bounds__(256) void transpose_cvt(const float* __restrict__ src,
                                                     u16* __restrict__ dst,
                                                     int R, int C) {
  __shared__ float t[64 * 65];
  const int z = blockIdx.z;
  const float* s = src + (long)z * R * C;
  u16* d = dst + (long)z * R * C;
  const int s0 = blockIdx.x * 64, c0 = blockIdx.y * 64;  // s0: src col, c0: src row
  const int tc = threadIdx.x >> 4;        // 0..15
  const int tx = (threadIdx.x & 15) * 4;  // 0,4,...,60
#pragma unroll
  for (int it = 0; it < 4; ++it) {
    const int c = tc + it * 16;
    float4 v = *(const float4*)(s + (long)(c0 + c) * C + s0 + tx);
    float* q = t + c * 65 + tx;
    q[0] = v.x; q[1] = v.y; q[2] = v.z; q[3] = v.w;
  }
  __syncthreads();
#pragma unroll
  for (int it = 0; it < 4; ++it) {
    const int srow = tc + it * 16;
    u16 o[4];
#pragma unroll
    for (int k2 = 0; k2 < 4; ++k2) o[k2] = f2bf(t[(tx + k2) * 65 + srow]);
    *(ushort4*)(d + (long)(s0 + srow) * R + c0 + tx) = *(ushort4*)o;
  }
}

// ---------------- pipelined bf16 GEMM: C = alpha*(A.B^T) + bias ----------------
// A: (M,K) bf16 rows at stride lda, B: (N,K) bf16 rows at stride ldb.
// Grid: (N/128, M/128, batch*ksplit).  BIAS_MODE: 0 none, 1 per-col, 2 per-row.
// OUT_MODE: 0 f32 (split-K slab at kc*sSlab), 1 bf16, 2 f16.
// SWIZ: L2 swizzle for 16x8 grids.  bdivA: A/bias advance every bdivA batches.
// DUAL: batches [nbat,2*nbat) use {A+aoff2, B2/ldb2/sB2, C2, alpha2, K2}.
// FUSEA: A is att(f16); Am is mixed(f16); st4 is per-row float4 stats
//   (amax, (1-TT)/asum, mmax, TT/msum); staging computes blended bf16 on the
//   fly (bit-identical to the old blend_softmax output).
// BF32: B is fp32; staging converts in-register (bit-identical to cvt_multi).
// K-loop: reg prefetch of tile k+1 + double-buffered LDS -> ONE barrier per
// K-step (write buf[cur] overlaps other waves' MFMA on buf[cur^1]).
template<int BIAS_MODE, int RELU, int OUT_MODE, int SWIZ, int DUAL, int FUSEA, int BF32>
__global__ __launch_bounds__(256) void gemm_bt(
    const u16* __restrict__ A, const u16* __restrict__ B,
    void* __restrict__ C, const float* __restrict__ bias,
    float alpha, int N, int K, int lda, int ldb,
    long sA, long sB, long sC, long sBias, int ksplit, long sSlab, int bdivA,
    const u16* __restrict__ B2, int ldb2, long sB2, int aoff2,
    void* __restrict__ C2, float alpha2, int nbat, int K2,
    const u16* __restrict__ Am, const float* __restrict__ st4)
{
  __shared__ __attribute__((aligned(16))) u16 As[2][128 * 32];
  __shared__ __attribute__((aligned(16))) u16 Bs[2][128 * 32];
  const int bz = blockIdx.z;
  int b = bz / ksplit;
  const int kc = bz - b * ksplit;
  const u16* Bp = B; int ldbv = ldb; long sBv = sB; void* Cp = C;
  int aoff = 0; float al = alpha; int Kv = K;
  if (DUAL && b >= nbat) {
    b -= nbat; Bp = B2; ldbv = ldb2; sBv = sB2; Cp = C2;
    aoff = aoff2; al = alpha2; Kv = K2;
  }
  const int ba = b / bdivA;
  const int Klen = Kv / ksplit;
  const int k0 = kc * Klen;
  const u16* Ab = A + (long)ba * sA + aoff;
  const u16* Bb = Bp + (long)b * sBv;
  long tm, tn;
  if (SWIZ) {  // grid (16,8,z): co-resident blocks on one XCD share 2 n-tiles
    const int id = blockIdx.y * 16 + blockIdx.x;
    tm = (long)(id >> 4) * 128;
    tn = (long)(2 * (id & 7) + ((id >> 3) & 1)) * 128;
  } else {
    tm = (long)blockIdx.y * 128; tn = (long)blockIdx.x * 128;
  }
  const int tid = threadIdx.x;
  const int lane = tid & 63, wv = tid >> 6;
  const int wm = (wv >> 1) * 64, wn = (wv & 1) * 64;
  const int q = lane >> 4, r = lane & 15;
  const int ldr = lane >> 2;        // row within 16-row group
  const int ldc = (lane & 3) * 8;   // u16 offset within row (16B per lane)

  // global srcs for this wave's staging chunks (2 x 16 rows for A and B)
  const u16* gA0 = Ab + (tm + wv * 32 + ldr) * (long)lda + k0 + ldc;
  const u16* gA1 = gA0 + 16 * (long)lda;
  const u16* gB0 = Bb + (tn + wv * 32 + ldr) * (long)ldbv + k0 + ldc;
  const u16* gB1 = gB0 + 16 * (long)ldbv;
  const int dof = (wv * 32 + ldr) * 32 + ldc;  // LDS u16 offset within buffer

  const f32x4 zero4 = {0.0f, 0.0f, 0.0f, 0.0f};
  f32x4 acc[4][4];
#pragma unroll
  for (int i = 0; i < 4; ++i)
#pragma unroll
    for (int j = 0; j < 4; ++j) acc[i][j] = zero4;

  // prime tile 0 into registers
  uint4 ra0, ra1, rb0, rb1;
  f16x8 av0, av1, mv0, mv1;
  float4 qb0a, qb0b, qb1a, qb1b;
  const u16* gM0 = nullptr; const u16* gM1 = nullptr;
  const float* fB0 = nullptr; const float* fB1 = nullptr;
  float4 st0, st1;
  if (FUSEA) {
    gM0 = Am + (gA0 - A);
    gM1 = Am + (gA1 - A);
    av0 = *(const f16x8*)gA0; mv0 = *(const f16x8*)gM0;
    av1 = *(const f16x8*)gA1; mv1 = *(const f16x8*)gM1;
    const long r0 = (long)b * Tc + tm + wv * 32 + ldr;  // att rows = time rows
    st0 = ((const float4*)st4)[r0];
    st1 = ((const float4*)st4)[r0 + 16];
  } else {
    ra0 = *(const uint4*)gA0; ra1 = *(const uint4*)gA1;
  }
  if (BF32) {
    const float* Bf = (const float*)B + (long)b * sBv;
    fB0 = Bf + (tn + wv * 32 + ldr) * (long)ldbv + k0 + ldc;
    fB1 = fB0 + 16 * (long)ldbv;
    qb0a = *(const float4*)fB0; qb0b = *(const float4*)(fB0 + 4);
    qb1a = *(const float4*)fB1; qb1b = *(const float4*)(fB1 + 4);
  } else {
    rb0 = *(const uint4*)gB0; rb1 = *(const uint4*)gB1;
  }

  const int iters = Klen >> 5;
  int cur = 0;
  for (int it = 0; it < iters; ++it) {
    // write tile 'it' into buf[cur] (other waves may still be doing MFMA on
    // buf[cur^1]; last reads of buf[cur] were before the previous barrier)
    u16* a0 = As[cur] + dof;
    u16* b0 = Bs[cur] + dof;
    if (FUSEA) {  // blended = (1-TT)/asum*exp(a-amax) + TT/msum*exp(m-mmax)
      u16 oa[16];
#pragma unroll
      for (int e2 = 0; e2 < 8; ++e2) {
        oa[e2]     = f2bf(__expf((float)av0[e2] - st0.x) * st0.y
                        + __expf((float)mv0[e2] - st0.z) * st0.w);
        oa[8 + e2] = f2bf(__expf((float)av1[e2] - st1.x) * st1.y
                        + __expf((float)mv1[e2] - st1.z) * st1.w);
      }
      *(uint4*)a0 = ((uint4*)oa)[0]; *(uint4*)(a0 + 512) = ((uint4*)oa)[1];
    } else {
      *(uint4*)a0 = ra0; *(uint4*)(a0 + 512) = ra1;
    }
    if (BF32) {
      u16 ob[16];
#pragma unroll
      for (int e2 = 0; e2 < 4; ++e2) {
        ob[e2]      = f2bf(((const float*)&qb0a)[e2]);
        ob[4 + e2]  = f2bf(((const float*)&qb0b)[e2]);
        ob[8 + e2]  = f2bf(((const float*)&qb1a)[e2]);
        ob[12 + e2] = f2bf(((const float*)&qb1b)[e2]);
      }
      *(uint4*)b0 = ((uint4*)ob)[0]; *(uint4*)(b0 + 512) = ((uint4*)ob)[1];
    } else {
      *(uint4*)b0 = rb0; *(uint4*)(b0 + 512) = rb1;
    }
    if (it + 1 < iters) {            // prefetch tile k+1 (lands under MFMA below)
      const long o = (long)(it + 1) * 32;
      if (FUSEA) {
        av0 = *(const f16x8*)(gA0 + o); mv0 = *(const f16x8*)(gM0 + o);
        av1 = *(const f16x8*)(gA1 + o); mv1 = *(const f16x8*)(gM1 + o);
      } else {
        ra0 = *(const uint4*)(gA0 + o); ra1 = *(const uint4*)(gA1 + o);
      }
      if (BF32) {
        qb0a = *(const float4*)(fB0 + o); qb0b = *(const float4*)(fB0 + o + 4);
        qb1a = *(const float4*)(fB1 + o); qb1b = *(const float4*)(fB1 + o + 4);
      } else {
        rb0 = *(const uint4*)(gB0 + o); rb1 = *(const uint4*)(gB1 + o);
      }
    }
    __syncthreads();                 // lgkm drain: tile 'it' visible to all
    bf16x8 af[4], bfr[4];
#pragma unroll
    for (int i = 0; i < 4; ++i) {
      af[i]  = *(const bf16x8*)(As[cur] + (wm + i * 16 + r) * 32 + q * 8);
      bfr[i] = *(const bf16x8*)(Bs[cur] + (wn + i * 16 + r) * 32 + q * 8);
    }
#pragma unroll
    for (int i = 0; i < 4; ++i)
#pragma unroll
      for (int j = 0; j < 4; ++j)
        acc[i][j] = __builtin_amdgcn_mfma_f32_16x16x32_bf16(af[i], bfr[j], acc[i][j], 0, 0, 0);
    cur ^= 1;
  }

  // epilogue: D layout col=lane&15, row=(lane>>4)*4+reg  [measured m89/m91]
  const float* biasb = bias ? bias + (long)ba * sBias : nullptr;
#pragma unroll
  for (int i = 0; i < 4; ++i)
#pragma unroll
    for (int j = 0; j < 4; ++j)
#pragma unroll
      for (int v = 0; v < 4; ++v) {
        long row = tm + wm + i * 16 + q * 4 + v;
        long col = tn + wn + j * 16 + r;
        float val = acc[i][j][v] * al;
        if (BIAS_MODE == 1 && kc == 0) val += biasb[col];
        if (BIAS_MODE == 2 && kc == 0) val += biasb[row];
        if (RELU) val = fmaxf(val, 0.0f);
        long idx = (long)kc * sSlab + (long)b * sC + row * (long)N + col;
        if (OUT_MODE == 0)      ((float*)Cp)[idx] = val;
        else if (OUT_MODE == 1) ((u16*)Cp)[idx] = f2bf(val);
        else                    ((_Float16*)Cp)[idx] = (_Float16)val;
      }
}

// -------- per-row softmax stats for the fused blend: (amax, ca, mmax, cm) --------
__global__ __launch_bounds__(256) void blend_stats(
    const _Float16* __restrict__ att, const _Float16* __restrict__ mixed,
    float4* __restrict__ st)
{
  const long row = blockIdx.x;
  const int tid = threadIdx.x;
  f16x8 av = *(const f16x8*)(att + row * T1c + tid * 8);
  f16x8 mv = *(const f16x8*)(mixed + row * T1c + tid * 8);
  float a[8], m[8];
#pragma unroll
  for (int i = 0; i < 8; ++i) { a[i] = (float)av[i]; m[i] = (float)mv[i]; }
  float amax = a[0], mmax = m[0];
#pragma unroll
  for (int i = 1; i < 8; ++i) { amax = fmaxf(amax, a[i]); mmax = fmaxf(mmax, m[i]); }
#pragma unroll
  for (int off = 32; off > 0; off >>= 1) {
    amax = fmaxf(amax, __shfl_xor(amax, off));
    mmax = fmaxf(mmax, __shfl_xor(mmax, off));
  }
  __shared__ float red[8];
  const int lane = tid & 63, wv = tid >> 6;
  if (lane == 0) { red[wv] = amax; red[4 + wv] = mmax; }
  __syncthreads();
  amax = fmaxf(fmaxf(red[0], red[1]), fmaxf(red[2], red[3]));
  mmax = fmaxf(fmaxf(red[4], red[5]), fmaxf(red[6], red[7]));
  __syncthreads();
  float asum = 0.f, msum = 0.f;
#pragma unroll
  for (int i = 0; i < 8; ++i) {
    asum += __expf(a[i] - amax);
    msum += __expf(m[i] - mmax);
  }
#pragma unroll
  for (int off = 32; off > 0; off >>= 1) {
    asum += __shfl_xor(asum, off);
    msum += __shfl_xor(msum, off);
  }
  if (lane == 0) { red[wv] = asum; red[4 + wv] = msum; }
  __syncthreads();
  asum = red[0] + red[1] + red[2] + red[3];
  msum = red[4] + red[5] + red[6] + red[7];
  if (tid == 0) {
    float4 o;
    o.x = amax; o.y = (1.0f - TTc) / asum;
    o.z = mmax; o.w = TTc / msum;
    st[row] = o;
  }
}

// -------- x = LN(xin + sum of 4 split-K slabs) ; writes fp32 x and bf16 x --------
__global__ __launch_bounds__(384) void add_ln4(
    const float* __restrict__ xin, const float* __restrict__ zs,
    const float* __restrict__ g, const float* __restrict__ be,
    float* __restrict__ xout, u16* __restrict__ xbf)
{
  const long row = blockIdx.x;
  const int d = threadIdx.x;
  const long SL = (long)Bc * Tc * Dc;
  const long o = row * Dc + d;
  float v = xin[o] + zs[o] + zs[SL + o] + zs[2 * SL + o] + zs[3 * SL + o];
  float s = v, s2 = v * v;
#pragma unroll
  for (int off = 32; off > 0; off >>= 1) {
    s  += __shfl_xor(s, off);
    s2 += __shfl_xor(s2, off);
  }
  __shared__ float red[12];
  const int lane = d & 63, wv = d >> 6;
  if (lane == 0) { red[wv] = s; red[6 + wv] = s2; }
  __syncthreads();
  float S = 0.f, S2 = 0.f;
#pragma unroll
  for (int w = 0; w < 6; ++w) { S += red[w]; S2 += red[6 + w]; }
  const float mean = S * (1.0f / Dc);
  const float var  = S2 * (1.0f / Dc) - mean * mean;
  const float rstd = rsqrtf(var + EPSc);
  const float y = (v - mean) * rstd * g[d] + be[d];
  xout[o] = y;
  xbf[o] = f2bf(y);
}

extern "C" void kernel_launch(void* const* d_in, const int* in_sizes, int n_in,
                              void* d_out, int out_size, void* d_ws, size_t ws_size,
                              hipStream_t stream)
{
  const float* tgt     = (const float*)d_in[0];
  const float* memory  = (const float*)d_in[1];
  const float* score_c = (const float*)d_in[2];
  const float* out_c   = (const float*)d_in[3];
  const float* Wq  = (const float*)d_in[4];  const float* bq  = (const float*)d_in[5];
  const float* Wk  = (const float*)d_in[6];  const float* bk  = (const float*)d_in[7];
  const float* Wv  = (const float*)d_in[8];  const float* bv  = (const float*)d_in[9];
  const float* Wkn = (const float*)d_in[10]; const float* bkn = (const float*)d_in[11];
  const float* Wun = (const float*)d_in[12]; const float* bun = (const float*)d_in[13];
  const float* W1  = (const float*)d_in[14]; const float* b1  = (const float*)d_in[15];
  const float* W2  = (const float*)d_in[16]; const float* b2  = (const float*)d_in[17];
  const float* g1  = (const float*)d_in[18]; const float* be1 = (const float*)d_in[19];
  const float* g2  = (const float*)d_in[20]; const float* be2 = (const float*)d_in[21];
  (void)bk; (void)in_sizes; (void)n_in; (void)out_size;

  char* p = (char*)d_ws;
  auto alloc = [&](size_t b) { char* r = p; p += (b + 255) & ~(size_t)255; return r; };

  u16* wv_bf   = (u16*)alloc((size_t)Lc * Dc * DKc * 2);
  u16* wkn_bf  = (u16*)alloc((size_t)Lc * Dc * Dc * 2);
  u16* w1_bf   = (u16*)alloc((size_t)Lc * FFc * Dc * 2);
  u16* w2_bf   = (u16*)alloc((size_t)Lc * Dc * FFc * 2);
  u16* wqT     = (u16*)alloc((size_t)Lc * Dc * Dc * 2);      // [l][384][384] Wq^T
  u16* wkT     = (u16*)alloc((size_t)Lc * DKc * Dc * 2);     // [l][256][384] Wk^T
  u16* wqu_bf  = (u16*)alloc((size_t)Lc * QUc * Dc * 2);     // [l][640][384] = [WqkT; Wun]
  float* bqu   = (float*)alloc((size_t)Lc * QUc * 4);
  u16* mem_bf  = (u16*)alloc((size_t)Bc * T1c * DKc * 2);
  u16* x_bf    = (u16*)alloc((size_t)Bc * Tc * Dc * 2);
  float* xbuf  = (float*)alloc((size_t)Bc * Tc * Dc * 4);
  u16* qunk_bf = (u16*)alloc((size_t)Bc * Tc * QUc * 2);      // [B*T][640]
  u16* vT_all  = (u16*)alloc((size_t)Bc * Lc * Dc * T1c * 2); // [b][1536][2048]
  u16* knoT_all = (u16*)alloc((size_t)Lc * Bc * Dc * TCc * 2); // [l][b][384][1024]
  u16* M2T_all = (u16*)alloc((size_t)Lc * Bc * T1c * Dc * 2);  // [l][b][2048][384]
  u16* scT_all = (u16*)alloc((size_t)Lc * Bc * T1c * TCc * 2);
  _Float16* att   = (_Float16*)alloc((size_t)Bc * Tc * T1c * 2);
  _Float16* mixed = (_Float16*)alloc((size_t)Bc * Tc * T1c * 2);
  float4* stats = (float4*)alloc((size_t)Bc * Tc * 16);
  float* zslab = (float*)alloc((size_t)4 * Bc * Tc * Dc * 4);
  float* yslab = (float*)alloc((size_t)4 * Bc * Tc * Dc * 4);
  u16* h_bf    = (u16*)alloc((size_t)Bc * Tc * FFc * 2);

  if ((size_t)(p - (char*)d_ws) > ws_size) return;  // fail loudly (poisoned out)

  // ---- single multi-convert launch (out_c no longer converted: knoT reads f32) ----
  {
    CPack cp{}; int g = 0; long tot4 = 0;
    auto add = [&](const float* s, u16* d, long n) {
      cp.d[g].src = s; cp.d[g].dst = d; cp.d[g].n4 = n / 4; tot4 += n / 4; ++g;
    };
    add(Wv,  wv_bf,  (long)Lc * Dc * DKc);
    add(Wkn, wkn_bf, (long)Lc * Dc * Dc);
    add(W1,  w1_bf,  (long)Lc * FFc * Dc);
    add(W2,  w2_bf,  (long)Lc * Dc * FFc);
    add(memory, mem_bf, (long)Bc * T1c * DKc);
    add(tgt, x_bf, (long)Bc * Tc * Dc);
    for (int l = 0; l < Lc; ++l)  // Wun -> wqu rows [256..640)
      add(Wun + (long)l * Dc * Dc,
          wqu_bf + (long)l * QUc * Dc + (long)DKc * Dc, (long)Dc * Dc);
    cp.nd = g; cp.tot4 = tot4;
    cvt_multi<<<4096, 256, 0, stream>>>(cp);
  }

  // transposes: score_c (1024x2048 -> 2048x1024), Wq (384x384), Wk (384x256)
  transpose_cvt<<<dim3(T1c / 64, TCc / 64, Lc * Bc), 256, 0, stream>>>(
      score_c, scT_all, TCc, T1c);
  transpose_cvt<<<dim3(Dc / 64, Dc / 64, Lc), 256, 0, stream>>>(Wq, wqT, Dc, Dc);
  transpose_cvt<<<dim3(DKc / 64, Dc / 64, Lc), 256, 0, stream>>>(Wk, wkT, Dc, DKc);

  const float scale = 1.0f / sqrtf((float)Dc);
  const long SLAB = (long)Bc * Tc * Dc;

  // WqkT[l] = WkT[l] . WqT[l]^T  (256 x 384, K=384) -> wqu rows [0..256)
  gemm_bt<0,0,1,0,0,0,0><<<dim3(Dc/128, DKc/128, Lc), 256, 0, stream>>>(
      wkT, wqT, wqu_bf, nullptr, 1.0f, Dc, Dc, Dc, Dc,
      (long)DKc*Dc, (long)Dc*Dc, (long)QUc*Dc, 0, 1, 0, 1,
      nullptr, 0, 0, 0, nullptr, 0.f, 0, Dc, nullptr, nullptr);
  // bqu[l] = [bq.Wk ; bun]
  make_bias<<<Lc, QUc, 0, stream>>>(bq, bun, wkT, bqu);

  // vT_all[b] = Wv_all . memory[b]^T + bv(row)  (1536 x 2048, K=256) x B
  gemm_bt<2,0,1,0,0,0,0><<<dim3(T1c/128, Lc*Dc/128, Bc), 256, 0, stream>>>(
      wv_bf, mem_bf, vT_all, bv, 1.0f, T1c, DKc, DKc, DKc,
      0, (long)T1c*DKc, (long)Lc*Dc*T1c, 0, 1, 0, 1,
      nullptr, 0, 0, 0, nullptr, 0.f, 0, DKc, nullptr, nullptr);
  // knoT_all[l][b] = Wkn[l] . out_c[l][b]^T + bkn[l](row)  (384 x 1024, K=384) x16
  // B operand read directly from fp32 out_c (BF32 staging)
  gemm_bt<2,0,1,0,0,0,1><<<dim3(TCc/128, Dc/128, Lc*Bc), 256, 0, stream>>>(
      wkn_bf, (const u16*)out_c, knoT_all, bkn, 1.0f, TCc, Dc, Dc, Dc,
      (long)Dc*Dc, (long)TCc*Dc, (long)Dc*TCc, Dc, 1, 0, Bc,
      nullptr, 0, 0, 0, nullptr, 0.f, 0, Dc, nullptr, nullptr);
  // M2T_all[l][b] = scale * scT[l][b] . knoT[l][b]^T  (2048 x 384, K=1024) x16
  gemm_bt<0,0,1,0,0,0,0><<<dim3(Dc/128, T1c/128, Lc*Bc), 256, 0, stream>>>(
      scT_all, knoT_all, M2T_all, nullptr, scale, Dc, TCc, TCc, TCc,
      (long)T1c*TCc, (long)Dc*TCc, (long)T1c*Dc, 0, 1, 0, 1,
      nullptr, 0, 0, 0, nullptr, 0.f, 0, TCc, nullptr, nullptr);

  for (int l = 0; l < Lc; ++l) {
    // qunk = x . [WqkT;Wun]^T + [bq.Wk;bun]   (4096 x 640, K=384)
    gemm_bt<1,0,1,0,0,0,0><<<dim3(QUc/128, Bc*Tc/128, 1), 256, 0, stream>>>(
        x_bf, wqu_bf + (long)l*QUc*Dc, qunk_bf, bqu + l*QUc,
        1.0f, QUc, Dc, Dc, Dc, 0, 0, 0, 0, 1, 0, 1,
        nullptr, 0, 0, 0, nullptr, 0.f, 0, Dc, nullptr, nullptr);
    // DUAL: att[b] = scale * qk[b].mem[b]^T (K=256)   [bk dropped: softmax
    //       row-shift invariance]  AND  mixed[b] = unk[b].M2T[l][b]^T (K=384)
    gemm_bt<0,0,2,1,1,0,0><<<dim3(T1c/128, Tc/128, 2*Bc), 256, 0, stream>>>(
        qunk_bf, mem_bf, att, nullptr, scale, T1c, DKc, QUc, DKc,
        (long)Tc*QUc, (long)T1c*DKc, (long)Tc*T1c, 0, 1, 0, 1,
        M2T_all + (long)l*Bc*T1c*Dc, Dc, (long)T1c*Dc, DKc, mixed, 1.0f, Bc, Dc,
        nullptr, nullptr);
    // per-row stats for the fused blend
    blend_stats<<<Bc*Tc, 256, 0, stream>>>(att, mixed, stats);
    // z[b] = blended[b] . vT[l][b]^T  (1024 x 384, K=2048), split-K=4 slabs;
    // blended computed on the fly from att/mixed/stats (FUSEA)
    gemm_bt<0,0,0,0,0,1,0><<<dim3(Dc/128, Tc/128, Bc*4), 256, 0, stream>>>(
        (const u16*)att, vT_all + (long)l*Dc*T1c, zslab, nullptr, 1.0f,
        Dc, T1c, T1c, T1c, (long)Tc*T1c, (long)Lc*Dc*T1c, (long)Tc*Dc, 0, 4, SLAB, 1,
        nullptr, 0, 0, 0, nullptr, 0.f, 0, T1c,
        (const u16*)mixed, (const float*)stats);
    // x = LN(x + sum(zslab))
    add_ln4<<<Bc*Tc, Dc, 0, stream>>>(
        (l == 0) ? tgt : xbuf, zslab, g1 + l*Dc, be1 + l*Dc, xbuf, x_bf);
    // h = relu(x . W1^T + b1)   (4096 x 1536, K=384) bf16
    gemm_bt<1,1,1,0,0,0,0><<<dim3(FFc/128, Bc*Tc/128, 1), 256, 0, stream>>>(
        x_bf, w1_bf + (long)l*FFc*Dc, h_bf, b1 + l*FFc, 1.0f,
        FFc, Dc, Dc, Dc, 0, 0, 0, 0, 1, 0, 1,
        nullptr, 0, 0, 0, nullptr, 0.f, 0, Dc, nullptr, nullptr);
    // y2 = h . W2^T + b2   (4096 x 384, K=1536), split-K=4 slabs
    gemm_bt<1,0,0,0,0,0,0><<<dim3(Dc/128, Bc*Tc/128, 4), 256, 0, stream>>>(
        h_bf, w2_bf + (long)l*Dc*FFc, yslab, b2 + l*Dc, 1.0f,
        Dc, FFc, FFc, FFc, 0, 0, 0, 0, 4, SLAB, 1,
        nullptr, 0, 0, 0, nullptr, 0.f, 0, FFc, nullptr, nullptr);
    // x = LN(x + sum(yslab)) ; last layer writes d_out
    add_ln4<<<Bc*Tc, Dc, 0, stream>>>(
        xbuf, yslab, g2 + l*Dc, be2 + l*Dc,
        (l == Lc - 1) ? (float*)d_out : xbuf, x_bf);
  }
}

// Round 8
// 968.638 us; speedup vs baseline: 1.0049x; 1.0049x over previous
//
#include <hip/hip_runtime.h>
#include <math.h>

#define Lc 4
#define Bc 4
#define Tc 1024
#define TCc 1024
#define T1c 2048
#define Dc 384
#define DKc 256
#define FFc 1536
#define TTc 0.1f
#define EPSc 1e-5f
#define QUc 640   // [qk(256); unk(384)] fused projection width
#define KKPB 8    // kk columns per weight_prep block

typedef unsigned short u16;
typedef __attribute__((ext_vector_type(8))) __bf16 bf16x8;
typedef __attribute__((ext_vector_type(8))) _Float16 f16x8;
typedef __attribute__((ext_vector_type(4))) float f32x4;

__device__ inline u16 f2bf(float f) {
  union { float f; unsigned u; } x; x.f = f;
  unsigned r = x.u + 0x7fffu + ((x.u >> 16) & 1u);
  return (u16)(r >> 16);
}

// ---------------- multi-tensor fp32 -> bf16 convert (float4/ushort4) ----------------
struct CDesc { const float* src; u16* dst; long n4; };
struct CPack { CDesc d[16]; long tot4; int nd; };

__global__ void cvt_multi(CPack P) {
  long i = (long)blockIdx.x * 256 + threadIdx.x;
  const long st = (long)gridDim.x * 256;
  for (; i < P.tot4; i += st) {
    long r = i; int g = 0;
    while (g < P.nd - 1 && r >= P.d[g].n4) { r -= P.d[g].n4; ++g; }
    float4 v = ((const float4*)P.d[g].src)[r];
    ushort4 o;
    o.x = f2bf(v.x); o.y = f2bf(v.y); o.z = f2bf(v.z); o.w = f2bf(v.w);
    ((ushort4*)P.d[g].dst)[r] = o;
  }
}

// ---- fused att-weight prep: replaces {transpose Wq, transpose Wk, WqkT GEMM,
// make_bias}.  wqu rows [0..256): WqkT[kk,d] = sum_e Wk[e,kk]*Wq[e,d] (f32 dot,
// one bf16 round).  bqu[l][kk] = sum_e bq[e]*Wk[e,kk]; bqu[l][256..640) = bun.
__global__ __launch_bounds__(384) void weight_prep(
    const float* __restrict__ Wq, const float* __restrict__ Wk,
    const float* __restrict__ bq, const float* __restrict__ bun,
    u16* __restrict__ wqu, float* __restrict__ bqu)
{
  const int kk0 = blockIdx.x * KKPB;   // 0,8,...,248
  const int l   = blockIdx.y;
  const int d   = threadIdx.x;         // 0..383
  const float* wq = Wq + (long)l * Dc * Dc;
  const float* wk = Wk + (long)l * Dc * DKc;
  const float* bb = bq + l * Dc;
  float s[KKPB], sb[KKPB];
#pragma unroll
  for (int j = 0; j < KKPB; ++j) { s[j] = 0.f; sb[j] = 0.f; }
  for (int e = 0; e < Dc; ++e) {
    const float xq = wq[(long)e * Dc + d];
    const float be = bb[e];
#pragma unroll
    for (int j = 0; j < KKPB; ++j) {
      const float wke = wk[(long)e * DKc + kk0 + j];
      s[j]  += wke * xq;
      sb[j] += wke * be;
    }
  }
#pragma unroll
  for (int j = 0; j < KKPB; ++j) {
    wqu[(long)l * QUc * Dc + (long)(kk0 + j) * Dc + d] = f2bf(s[j]);
    if (d == 0) bqu[l * QUc + kk0 + j] = sb[j];
  }
  if (blockIdx.x == 0) bqu[l * QUc + DKc + d] = bun[l * Dc + d];
}

// ------- src[z] (R,C) fp32 -> dst[z] (C,R) bf16, 64x64 tiles -------
// grid (C/64, R/64, batch)
__global__ __launch_bounds__(256) void transpose_cvt(const float* __restrict__ src,
                                                     u16* __restrict__ dst,
                                                     int R, int C) {
  __shared__ float t[64 * 65];
  const int z = blockIdx.z;
  const float* s = src + (long)z * R * C;
  u16* d = dst + (long)z * R * C;
  const int s0 = blockIdx.x * 64, c0 = blockIdx.y * 64;  // s0: src col, c0: src row
  const int tc = threadIdx.x >> 4;        // 0..15
  const int tx = (threadIdx.x & 15) * 4;  // 0,4,...,60
#pragma unroll
  for (int it = 0; it < 4; ++it) {
    const int c = tc + it * 16;
    float4 v = *(const float4*)(s + (long)(c0 + c) * C + s0 + tx);
    float* q = t + c * 65 + tx;
    q[0] = v.x; q[1] = v.y; q[2] = v.z; q[3] = v.w;
  }
  __syncthreads();
#pragma unroll
  for (int it = 0; it < 4; ++it) {
    const int srow = tc + it * 16;
    u16 o[4];
#pragma unroll
    for (int k2 = 0; k2 < 4; ++k2) o[k2] = f2bf(t[(tx + k2) * 65 + srow]);
    *(ushort4*)(d + (long)(s0 + srow) * R + c0 + tx) = *(ushort4*)o;
  }
}

// ---------------- pipelined bf16 GEMM: C = alpha*(A.B^T) + bias ----------------
// A: (M,K) bf16 rows at stride lda, B: (N,K) bf16 rows at stride ldb.
// Grid: (N/128, M/128, batch*ksplit).  BIAS_MODE: 0 none, 1 per-col, 2 per-row.
// OUT_MODE: 0 f32 (split-K slab at kc*sSlab), 1 bf16, 2 f16.
// SWIZ: L2 swizzle for 16x8 grids.  bdivA: A/bias advance every bdivA batches.
// DUAL: batches [nbat,2*nbat) use {A+aoff2, B2/ldb2/sB2, C2, alpha2, K2}.
// K-loop: reg prefetch of tile k+1 + double-buffered LDS -> ONE barrier per
// K-step (write buf[cur] overlaps other waves' MFMA on buf[cur^1]).
template<int BIAS_MODE, int RELU, int OUT_MODE, int SWIZ, int DUAL>
__global__ __launch_bounds__(256) void gemm_bt(
    const u16* __restrict__ A, const u16* __restrict__ B,
    void* __restrict__ C, const float* __restrict__ bias,
    float alpha, int N, int K, int lda, int ldb,
    long sA, long sB, long sC, long sBias, int ksplit, long sSlab, int bdivA,
    const u16* __restrict__ B2, int ldb2, long sB2, int aoff2,
    void* __restrict__ C2, float alpha2, int nbat, int K2)
{
  __shared__ __attribute__((aligned(16))) u16 As[2][128 * 32];
  __shared__ __attribute__((aligned(16))) u16 Bs[2][128 * 32];
  const int bz = blockIdx.z;
  int b = bz / ksplit;
  const int kc = bz - b * ksplit;
  const u16* Bp = B; int ldbv = ldb; long sBv = sB; void* Cp = C;
  int aoff = 0; float al = alpha; int Kv = K;
  if (DUAL && b >= nbat) {
    b -= nbat; Bp = B2; ldbv = ldb2; sBv = sB2; Cp = C2;
    aoff = aoff2; al = alpha2; Kv = K2;
  }
  const int ba = b / bdivA;
  const int Klen = Kv / ksplit;
  const int k0 = kc * Klen;
  const u16* Ab = A + (long)ba * sA + aoff;
  const u16* Bb = Bp + (long)b * sBv;
  long tm, tn;
  if (SWIZ) {  // grid (16,8,z): co-resident blocks on one XCD share 2 n-tiles
    const int id = blockIdx.y * 16 + blockIdx.x;
    tm = (long)(id >> 4) * 128;
    tn = (long)(2 * (id & 7) + ((id >> 3) & 1)) * 128;
  } else {
    tm = (long)blockIdx.y * 128; tn = (long)blockIdx.x * 128;
  }
  const int tid = threadIdx.x;
  const int lane = tid & 63, wv = tid >> 6;
  const int wm = (wv >> 1) * 64, wn = (wv & 1) * 64;
  const int q = lane >> 4, r = lane & 15;
  const int ldr = lane >> 2;        // row within 16-row group
  const int ldc = (lane & 3) * 8;   // u16 offset within row (16B per lane)

  // global srcs for this wave's staging chunks (2 x 16 rows for A and B)
  const u16* gA0 = Ab + (tm + wv * 32 + ldr) * (long)lda + k0 + ldc;
  const u16* gA1 = gA0 + 16 * (long)lda;
  const u16* gB0 = Bb + (tn + wv * 32 + ldr) * (long)ldbv + k0 + ldc;
  const u16* gB1 = gB0 + 16 * (long)ldbv;
  const int dof = (wv * 32 + ldr) * 32 + ldc;  // LDS u16 offset within buffer

  const f32x4 zero4 = {0.0f, 0.0f, 0.0f, 0.0f};
  f32x4 acc[4][4];
#pragma unroll
  for (int i = 0; i < 4; ++i)
#pragma unroll
    for (int j = 0; j < 4; ++j) acc[i][j] = zero4;

  // prime tile 0 into registers
  uint4 ra0 = *(const uint4*)gA0;
  uint4 ra1 = *(const uint4*)gA1;
  uint4 rb0 = *(const uint4*)gB0;
  uint4 rb1 = *(const uint4*)gB1;

  const int iters = Klen >> 5;
  int cur = 0;
  for (int it = 0; it < iters; ++it) {
    // write tile 'it' into buf[cur] (other waves may still be doing MFMA on
    // buf[cur^1]; last reads of buf[cur] were before the previous barrier)
    u16* a0 = As[cur] + dof;
    u16* b0 = Bs[cur] + dof;
    *(uint4*)a0 = ra0; *(uint4*)(a0 + 512) = ra1;
    *(uint4*)b0 = rb0; *(uint4*)(b0 + 512) = rb1;
    if (it + 1 < iters) {            // prefetch tile k+1 (lands under MFMA below)
      const long o = (long)(it + 1) * 32;
      ra0 = *(const uint4*)(gA0 + o);
      ra1 = *(const uint4*)(gA1 + o);
      rb0 = *(const uint4*)(gB0 + o);
      rb1 = *(const uint4*)(gB1 + o);
    }
    __syncthreads();                 // lgkm drain: tile 'it' visible to all
    bf16x8 af[4], bfr[4];
#pragma unroll
    for (int i = 0; i < 4; ++i) {
      af[i]  = *(const bf16x8*)(As[cur] + (wm + i * 16 + r) * 32 + q * 8);
      bfr[i] = *(const bf16x8*)(Bs[cur] + (wn + i * 16 + r) * 32 + q * 8);
    }
#pragma unroll
    for (int i = 0; i < 4; ++i)
#pragma unroll
      for (int j = 0; j < 4; ++j)
        acc[i][j] = __builtin_amdgcn_mfma_f32_16x16x32_bf16(af[i], bfr[j], acc[i][j], 0, 0, 0);
    cur ^= 1;
  }

  // epilogue: D layout col=lane&15, row=(lane>>4)*4+reg  [measured m89/m91]
  const float* biasb = bias ? bias + (long)ba * sBias : nullptr;
#pragma unroll
  for (int i = 0; i < 4; ++i)
#pragma unroll
    for (int j = 0; j < 4; ++j)
#pragma unroll
      for (int v = 0; v < 4; ++v) {
        long row = tm + wm + i * 16 + q * 4 + v;
        long col = tn + wn + j * 16 + r;
        float val = acc[i][j][v] * al;
        if (BIAS_MODE == 1 && kc == 0) val += biasb[col];
        if (BIAS_MODE == 2 && kc == 0) val += biasb[row];
        if (RELU) val = fmaxf(val, 0.0f);
        long idx = (long)kc * sSlab + (long)b * sC + row * (long)N + col;
        if (OUT_MODE == 0)      ((float*)Cp)[idx] = val;
        else if (OUT_MODE == 1) ((u16*)Cp)[idx] = f2bf(val);
        else                    ((_Float16*)Cp)[idx] = (_Float16)val;
      }
}

// -------- blended = TT*softmax(mixed) + (1-TT)*softmax(att), rows of T1 --------
// each thread owns 8 contiguous f16 (16B vector loads/stores)
__global__ __launch_bounds__(256) void blend_softmax(
    const _Float16* __restrict__ att, const _Float16* __restrict__ mixed,
    u16* __restrict__ out)
{
  const long row = blockIdx.x;
  const int tid = threadIdx.x;
  f16x8 av = *(const f16x8*)(att + row * T1c + tid * 8);
  f16x8 mv = *(const f16x8*)(mixed + row * T1c + tid * 8);
  float a[8], m[8];
#pragma unroll
  for (int i = 0; i < 8; ++i) { a[i] = (float)av[i]; m[i] = (float)mv[i]; }
  float amax = a[0], mmax = m[0];
#pragma unroll
  for (int i = 1; i < 8; ++i) { amax = fmaxf(amax, a[i]); mmax = fmaxf(mmax, m[i]); }
#pragma unroll
  for (int off = 32; off > 0; off >>= 1) {
    amax = fmaxf(amax, __shfl_xor(amax, off));
    mmax = fmaxf(mmax, __shfl_xor(mmax, off));
  }
  __shared__ float red[8];
  const int lane = tid & 63, wv = tid >> 6;
  if (lane == 0) { red[wv] = amax; red[4 + wv] = mmax; }
  __syncthreads();
  amax = fmaxf(fmaxf(red[0], red[1]), fmaxf(red[2], red[3]));
  mmax = fmaxf(fmaxf(red[4], red[5]), fmaxf(red[6], red[7]));
  __syncthreads();
  float asum = 0.f, msum = 0.f;
#pragma unroll
  for (int i = 0; i < 8; ++i) {
    a[i] = __expf(a[i] - amax); asum += a[i];
    m[i] = __expf(m[i] - mmax); msum += m[i];
  }
#pragma unroll
  for (int off = 32; off > 0; off >>= 1) {
    asum += __shfl_xor(asum, off);
    msum += __shfl_xor(msum, off);
  }
  if (lane == 0) { red[wv] = asum; red[4 + wv] = msum; }
  __syncthreads();
  asum = red[0] + red[1] + red[2] + red[3];
  msum = red[4] + red[5] + red[6] + red[7];
  const float ca = (1.0f - TTc) / asum, cm = TTc / msum;
  u16 o[8];
#pragma unroll
  for (int i = 0; i < 8; ++i) o[i] = f2bf(a[i] * ca + m[i] * cm);
  *(uint4*)(out + row * T1c + tid * 8) = *(uint4*)o;
}

// -------- x = LN(xin + sum of 4 split-K slabs) ; writes fp32 x and bf16 x --------
__global__ __launch_bounds__(384) void add_ln4(
    const float* __restrict__ xin, const float* __restrict__ zs,
    const float* __restrict__ g, const float* __restrict__ be,
    float* __restrict__ xout, u16* __restrict__ xbf)
{
  const long row = blockIdx.x;
  const int d = threadIdx.x;
  const long SL = (long)Bc * Tc * Dc;
  const long o = row * Dc + d;
  float v = xin[o] + zs[o] + zs[SL + o] + zs[2 * SL + o] + zs[3 * SL + o];
  float s = v, s2 = v * v;
#pragma unroll
  for (int off = 32; off > 0; off >>= 1) {
    s  += __shfl_xor(s, off);
    s2 += __shfl_xor(s2, off);
  }
  __shared__ float red[12];
  const int lane = d & 63, wv = d >> 6;
  if (lane == 0) { red[wv] = s; red[6 + wv] = s2; }
  __syncthreads();
  float S = 0.f, S2 = 0.f;
#pragma unroll
  for (int w = 0; w < 6; ++w) { S += red[w]; S2 += red[6 + w]; }
  const float mean = S * (1.0f / Dc);
  const float var  = S2 * (1.0f / Dc) - mean * mean;
  const float rstd = rsqrtf(var + EPSc);
  const float y = (v - mean) * rstd * g[d] + be[d];
  xout[o] = y;
  xbf[o] = f2bf(y);
}

extern "C" void kernel_launch(void* const* d_in, const int* in_sizes, int n_in,
                              void* d_out, int out_size, void* d_ws, size_t ws_size,
                              hipStream_t stream)
{
  const float* tgt     = (const float*)d_in[0];
  const float* memory  = (const float*)d_in[1];
  const float* score_c = (const float*)d_in[2];
  const float* out_c   = (const float*)d_in[3];
  const float* Wq  = (const float*)d_in[4];  const float* bq  = (const float*)d_in[5];
  const float* Wk  = (const float*)d_in[6];  const float* bk  = (const float*)d_in[7];
  const float* Wv  = (const float*)d_in[8];  const float* bv  = (const float*)d_in[9];
  const float* Wkn = (const float*)d_in[10]; const float* bkn = (const float*)d_in[11];
  const float* Wun = (const float*)d_in[12]; const float* bun = (const float*)d_in[13];
  const float* W1  = (const float*)d_in[14]; const float* b1  = (const float*)d_in[15];
  const float* W2  = (const float*)d_in[16]; const float* b2  = (const float*)d_in[17];
  const float* g1  = (const float*)d_in[18]; const float* be1 = (const float*)d_in[19];
  const float* g2  = (const float*)d_in[20]; const float* be2 = (const float*)d_in[21];
  (void)bk; (void)in_sizes; (void)n_in; (void)out_size;

  char* p = (char*)d_ws;
  auto alloc = [&](size_t b) { char* r = p; p += (b + 255) & ~(size_t)255; return r; };

  u16* wv_bf   = (u16*)alloc((size_t)Lc * Dc * DKc * 2);
  u16* wkn_bf  = (u16*)alloc((size_t)Lc * Dc * Dc * 2);
  u16* w1_bf   = (u16*)alloc((size_t)Lc * FFc * Dc * 2);
  u16* w2_bf   = (u16*)alloc((size_t)Lc * Dc * FFc * 2);
  u16* wqu_bf  = (u16*)alloc((size_t)Lc * QUc * Dc * 2);     // [l][640][384] = [WqkT; Wun]
  float* bqu   = (float*)alloc((size_t)Lc * QUc * 4);
  u16* mem_bf  = (u16*)alloc((size_t)Bc * T1c * DKc * 2);
  u16* outc_bf = (u16*)alloc((size_t)Lc * Bc * TCc * Dc * 2);
  u16* x_bf    = (u16*)alloc((size_t)Bc * Tc * Dc * 2);
  float* xbuf  = (float*)alloc((size_t)Bc * Tc * Dc * 4);
  u16* qunk_bf = (u16*)alloc((size_t)Bc * Tc * QUc * 2);      // [B*T][640]
  u16* vT_all  = (u16*)alloc((size_t)Bc * Lc * Dc * T1c * 2); // [b][1536][2048]
  u16* knoT_all = (u16*)alloc((size_t)Lc * Bc * Dc * TCc * 2); // [l][b][384][1024]
  u16* M2T_all = (u16*)alloc((size_t)Lc * Bc * T1c * Dc * 2);  // [l][b][2048][384]
  u16* scT_all = (u16*)alloc((size_t)Lc * Bc * T1c * TCc * 2);
  _Float16* att   = (_Float16*)alloc((size_t)Bc * Tc * T1c * 2);
  _Float16* mixed = (_Float16*)alloc((size_t)Bc * Tc * T1c * 2);
  u16* blended = (u16*)alloc((size_t)Bc * Tc * T1c * 2);
  float* zslab = (float*)alloc((size_t)4 * Bc * Tc * Dc * 4);
  float* yslab = (float*)alloc((size_t)4 * Bc * Tc * Dc * 4);
  u16* h_bf    = (u16*)alloc((size_t)Bc * Tc * FFc * 2);

  if ((size_t)(p - (char*)d_ws) > ws_size) return;  // fail loudly (poisoned out)

  // ---- single multi-convert launch ----
  {
    CPack cp{}; int g = 0; long tot4 = 0;
    auto add = [&](const float* s, u16* d, long n) {
      cp.d[g].src = s; cp.d[g].dst = d; cp.d[g].n4 = n / 4; tot4 += n / 4; ++g;
    };
    add(Wv,  wv_bf,  (long)Lc * Dc * DKc);
    add(Wkn, wkn_bf, (long)Lc * Dc * Dc);
    add(W1,  w1_bf,  (long)Lc * FFc * Dc);
    add(W2,  w2_bf,  (long)Lc * Dc * FFc);
    add(memory, mem_bf, (long)Bc * T1c * DKc);
    add(out_c, outc_bf, (long)Lc * Bc * TCc * Dc);
    add(tgt, x_bf, (long)Bc * Tc * Dc);
    for (int l = 0; l < Lc; ++l)  // Wun -> wqu rows [256..640)
      add(Wun + (long)l * Dc * Dc,
          wqu_bf + (long)l * QUc * Dc + (long)DKc * Dc, (long)Dc * Dc);
    cp.nd = g; cp.tot4 = tot4;
    cvt_multi<<<4096, 256, 0, stream>>>(cp);
  }

  // score_c transpose (1024x2048 -> 2048x1024) x16
  transpose_cvt<<<dim3(T1c / 64, TCc / 64, Lc * Bc), 256, 0, stream>>>(
      score_c, scT_all, TCc, T1c);
  // fused att-weight prep: wqu rows [0..256) + bqu (replaces 4 dispatches)
  weight_prep<<<dim3(DKc / KKPB, Lc), 384, 0, stream>>>(Wq, Wk, bq, bun, wqu_bf, bqu);

  const float scale = 1.0f / sqrtf((float)Dc);
  const long SLAB = (long)Bc * Tc * Dc;

  // vT_all[b] = Wv_all . memory[b]^T + bv(row)  (1536 x 2048, K=256) x B
  gemm_bt<2,0,1,0,0><<<dim3(T1c/128, Lc*Dc/128, Bc), 256, 0, stream>>>(
      wv_bf, mem_bf, vT_all, bv, 1.0f, T1c, DKc, DKc, DKc,
      0, (long)T1c*DKc, (long)Lc*Dc*T1c, 0, 1, 0, 1,
      nullptr, 0, 0, 0, nullptr, 0.f, 0, DKc);
  // knoT_all[l][b] = Wkn[l] . out_c[l][b]^T + bkn[l](row)  (384 x 1024, K=384) x16
  gemm_bt<2,0,1,0,0><<<dim3(TCc/128, Dc/128, Lc*Bc), 256, 0, stream>>>(
      wkn_bf, outc_bf, knoT_all, bkn, 1.0f, TCc, Dc, Dc, Dc,
      (long)Dc*Dc, (long)TCc*Dc, (long)Dc*TCc, Dc, 1, 0, Bc,
      nullptr, 0, 0, 0, nullptr, 0.f, 0, Dc);
  // M2T_all[l][b] = scale * scT[l][b] . knoT[l][b]^T  (2048 x 384, K=1024) x16
  gemm_bt<0,0,1,0,0><<<dim3(Dc/128, T1c/128, Lc*Bc), 256, 0, stream>>>(
      scT_all, knoT_all, M2T_all, nullptr, scale, Dc, TCc, TCc, TCc,
      (long)T1c*TCc, (long)Dc*TCc, (long)T1c*Dc, 0, 1, 0, 1,
      nullptr, 0, 0, 0, nullptr, 0.f, 0, TCc);

  for (int l = 0; l < Lc; ++l) {
    // qunk = x . [WqkT;Wun]^T + [bq.Wk;bun]   (4096 x 640, K=384)
    gemm_bt<1,0,1,0,0><<<dim3(QUc/128, Bc*Tc/128, 1), 256, 0, stream>>>(
        x_bf, wqu_bf + (long)l*QUc*Dc, qunk_bf, bqu + l*QUc,
        1.0f, QUc, Dc, Dc, Dc, 0, 0, 0, 0, 1, 0, 1,
        nullptr, 0, 0, 0, nullptr, 0.f, 0, Dc);
    // DUAL: att[b] = scale * qk[b].mem[b]^T (K=256)   [bk dropped: softmax
    //       row-shift invariance]  AND  mixed[b] = unk[b].M2T[l][b]^T (K=384)
    gemm_bt<0,0,2,1,1><<<dim3(T1c/128, Tc/128, 2*Bc), 256, 0, stream>>>(
        qunk_bf, mem_bf, att, nullptr, scale, T1c, DKc, QUc, DKc,
        (long)Tc*QUc, (long)T1c*DKc, (long)Tc*T1c, 0, 1, 0, 1,
        M2T_all + (long)l*Bc*T1c*Dc, Dc, (long)T1c*Dc, DKc, mixed, 1.0f, Bc, Dc);
    // blended = TT*softmax(mixed) + (1-TT)*softmax(att)
    blend_softmax<<<Bc*Tc, 256, 0, stream>>>(att, mixed, blended);
    // z[b] = blended[b] . vT[l][b]^T   (1024 x 384, K=2048), split-K=4 slabs
    gemm_bt<0,0,0,0,0><<<dim3(Dc/128, Tc/128, Bc*4), 256, 0, stream>>>(
        blended, vT_all + (long)l*Dc*T1c, zslab, nullptr, 1.0f,
        Dc, T1c, T1c, T1c, (long)Tc*T1c, (long)Lc*Dc*T1c, (long)Tc*Dc, 0, 4, SLAB, 1,
        nullptr, 0, 0, 0, nullptr, 0.f, 0, T1c);
    // x = LN(x + sum(zslab))
    add_ln4<<<Bc*Tc, Dc, 0, stream>>>(
        (l == 0) ? tgt : xbuf, zslab, g1 + l*Dc, be1 + l*Dc, xbuf, x_bf);
    // h = relu(x . W1^T + b1)   (4096 x 1536, K=384) bf16
    gemm_bt<1,1,1,0,0><<<dim3(FFc/128, Bc*Tc/128, 1), 256, 0, stream>>>(
        x_bf, w1_bf + (long)l*FFc*Dc, h_bf, b1 + l*FFc, 1.0f,
        FFc, Dc, Dc, Dc, 0, 0, 0, 0, 1, 0, 1,
        nullptr, 0, 0, 0, nullptr, 0.f, 0, Dc);
    // y2 = h . W2^T + b2   (4096 x 384, K=1536), split-K=4 slabs
    gemm_bt<1,0,0,0,0><<<dim3(Dc/128, Bc*Tc/128, 4), 256, 0, stream>>>(
        h_bf, w2_bf + (long)l*Dc*FFc, yslab, b2 + l*Dc, 1.0f,
        Dc, FFc, FFc, FFc, 0, 0, 0, 0, 4, SLAB, 1,
        nullptr, 0, 0, 0, nullptr, 0.f, 0, FFc);
    // x = LN(x + sum(yslab)) ; last layer writes d_out
    add_ln4<<<Bc*Tc, Dc, 0, stream>>>(
        xbuf, yslab, g2 + l*Dc, be2 + l*Dc,
        (l == Lc - 1) ? (float*)d_out : xbuf, x_bf);
  }
}

// Round 9
// 921.848 us; speedup vs baseline: 1.0559x; 1.0508x over previous
//
#include <hip/hip_runtime.h>
#include <math.h>

#define Lc 4
#define Bc 4
#define Tc 1024
#define TCc 1024
#define T1c 2048
#define Dc 384
#define DKc 256
#define FFc 1536
#define TTc 0.1f
#define EPSc 1e-5f
#define QUc 640   // [qk(256); unk(384)] fused projection width

typedef unsigned short u16;
typedef __attribute__((ext_vector_type(8))) __bf16 bf16x8;
typedef __attribute__((ext_vector_type(8))) _Float16 f16x8;
typedef __attribute__((ext_vector_type(4))) float f32x4;

__device__ inline u16 f2bf(float f) {
  union { float f; unsigned u; } x; x.f = f;
  unsigned r = x.u + 0x7fffu + ((x.u >> 16) & 1u);
  return (u16)(r >> 16);
}
__device__ inline float bf2f(u16 v) {
  union { unsigned u; float f; } x; x.u = (unsigned)v << 16; return x.f;
}

// ---------------- multi-tensor fp32 -> bf16 convert (float4/ushort4) ----------------
struct CDesc { const float* src; u16* dst; long n4; };
struct CPack { CDesc d[16]; long tot4; int nd; };

__global__ void cvt_multi(CPack P) {
  long i = (long)blockIdx.x * 256 + threadIdx.x;
  const long st = (long)gridDim.x * 256;
  for (; i < P.tot4; i += st) {
    long r = i; int g = 0;
    while (g < P.nd - 1 && r >= P.d[g].n4) { r -= P.d[g].n4; ++g; }
    float4 v = ((const float4*)P.d[g].src)[r];
    ushort4 o;
    o.x = f2bf(v.x); o.y = f2bf(v.y); o.z = f2bf(v.z); o.w = f2bf(v.w);
    ((ushort4*)P.d[g].dst)[r] = o;
  }
}

// bqu[l][0..256) = bq[l].Wk[l] (via WkT rows), bqu[l][256..640) = bun[l]
__global__ void make_bias(const float* __restrict__ bq, const float* __restrict__ bun,
                          const u16* __restrict__ wkT, float* __restrict__ bqu) {
  const int l = blockIdx.x, t = threadIdx.x;
  if (t < DKc) {
    const u16* w = wkT + ((long)l * DKc + t) * Dc;
    const float* b = bq + l * Dc;
    float s = 0.f;
    for (int e = 0; e < Dc; ++e) s += b[e] * bf2f(w[e]);
    bqu[l * QUc + t] = s;
  } else {
    bqu[l * QUc + t] = bun[l * Dc + (t - DKc)];
  }
}

// ------- src[z] (R,C) fp32 -> dst[z] (C,R) bf16, 64x64 tiles -------
// grid (maxC/64, R/64, nz1 + nz2).  z < nz1: {src,dst,C}; z >= nz1: {src2,dst2,C2}
// (C2 may be < gridDim.x*64: excess column-blocks return).
__global__ __launch_bounds__(256) void transpose_cvt(
    const float* __restrict__ src, u16* __restrict__ dst, int R, int C,
    const float* __restrict__ src2, u16* __restrict__ dst2, int C2, int nz1) {
  __shared__ float t[64 * 65];
  int z = blockIdx.z;
  const float* s; u16* d; int Cv;
  if (z < nz1) {
    s = src + (long)z * R * C;  d = dst + (long)z * R * C;  Cv = C;
  } else {
    z -= nz1; Cv = C2;
    if ((int)blockIdx.x * 64 >= Cv) return;
    s = src2 + (long)z * R * C2; d = dst2 + (long)z * R * C2;
  }
  const int s0 = blockIdx.x * 64, c0 = blockIdx.y * 64;  // s0: src col, c0: src row
  const int tc = threadIdx.x >> 4;        // 0..15
  const int tx = (threadIdx.x & 15) * 4;  // 0,4,...,60
#pragma unroll
  for (int it = 0; it < 4; ++it) {
    const int c = tc + it * 16;
    float4 v = *(const float4*)(s + (long)(c0 + c) * Cv + s0 + tx);
    float* q = t + c * 65 + tx;
    q[0] = v.x; q[1] = v.y; q[2] = v.z; q[3] = v.w;
  }
  __syncthreads();
#pragma unroll
  for (int it = 0; it < 4; ++it) {
    const int srow = tc + it * 16;
    u16 o[4];
#pragma unroll
    for (int k2 = 0; k2 < 4; ++k2) o[k2] = f2bf(t[(tx + k2) * 65 + srow]);
    *(ushort4*)(d + (long)(s0 + srow) * R + c0 + tx) = *(ushort4*)o;
  }
}

// ---------------- pipelined bf16 GEMM: C = alpha*(A.B^T) + bias ----------------
// A: (M,K) bf16 rows at stride lda, B: (N,K) bf16 rows at stride ldb.
// Grid: (N/128, M/128, batch*ksplit).  BIAS_MODE: 0 none, 1 per-col, 2 per-row.
// OUT_MODE: 0 f32 (split-K slab at kc*sSlab), 1 bf16, 2 f16.
// SWIZ: L2 swizzle for 16x8 grids.  bdivA: A/bias advance every bdivA batches.
// DUAL=1: batches [nbat,2*nbat) use {A+aoff2, B2/ldb2/sB2, C2, alpha2, K2}.
// DUAL=2: flat 1-D grid; blocks [0,nblk1) run GEMM1 {A,B,C,bias,...},
//   blocks [nblk1,..) run GEMM2 {A2,B2,C2,bias2,lda2/ldb2,K2,N2,...} — fuses two
//   independent batched GEMMs (same BIAS/OUT modes) into one dispatch.
// K-loop: reg prefetch of tile k+1 + double-buffered LDS -> ONE barrier per
// K-step (write buf[cur] overlaps other waves' MFMA on buf[cur^1]).
template<int BIAS_MODE, int RELU, int OUT_MODE, int SWIZ, int DUAL>
__global__ __launch_bounds__(256) void gemm_bt(
    const u16* __restrict__ A, const u16* __restrict__ B,
    void* __restrict__ C, const float* __restrict__ bias,
    float alpha, int N, int K, int lda, int ldb,
    long sA, long sB, long sC, long sBias, int ksplit, long sSlab, int bdivA,
    const u16* __restrict__ B2, int ldb2, long sB2, int aoff2,
    void* __restrict__ C2, float alpha2, int nbat, int K2,
    const u16* __restrict__ A2, int lda2, long sA2,
    const float* __restrict__ bias2, long sBias2, int bdivA2,
    int N2, long sC2, int nblk1, int nbx1, int nby1, int nbx2, int nby2)
{
  __shared__ __attribute__((aligned(16))) u16 As[2][128 * 32];
  __shared__ __attribute__((aligned(16))) u16 Bs[2][128 * 32];
  int b = 0, kc = 0, aoff_ = 0, lda_ = lda, ldb_ = ldb, Kv = K, Nv = N;
  int bdivA_ = bdivA;
  long sA_ = sA, sB_ = sB, sC_ = sC, sBias_ = sBias, tm, tn;
  const u16* Ap_ = A; const u16* Bp_ = B; void* Cp = C;
  const float* bias_ = bias; float al = alpha;
  if (DUAL == 2) {
    int flat = blockIdx.x;
    if (flat < nblk1) {
      const int per = nbx1 * nby1;
      b = flat / per; const int rem = flat - b * per;
      tm = (long)(rem / nbx1) * 128; tn = (long)(rem % nbx1) * 128;
    } else {
      flat -= nblk1;
      const int per = nbx2 * nby2;
      b = flat / per; const int rem = flat - b * per;
      tm = (long)(rem / nbx2) * 128; tn = (long)(rem % nbx2) * 128;
      Ap_ = A2; Bp_ = B2; Cp = C2; bias_ = bias2;
      lda_ = lda2; ldb_ = ldb2; sA_ = sA2; sB_ = sB2; sC_ = sC2; sBias_ = sBias2;
      bdivA_ = bdivA2; Kv = K2; Nv = N2;
    }
  } else {
    const int bz = blockIdx.z;
    b = bz / ksplit;
    kc = bz - b * ksplit;
    if (DUAL == 1 && b >= nbat) {
      b -= nbat; Bp_ = B2; ldb_ = ldb2; sB_ = sB2; Cp = C2;
      aoff_ = aoff2; al = alpha2; Kv = K2;
    }
    if (SWIZ) {  // grid (16,8,z): co-resident blocks on one XCD share 2 n-tiles
      const int id = blockIdx.y * 16 + blockIdx.x;
      tm = (long)(id >> 4) * 128;
      tn = (long)(2 * (id & 7) + ((id >> 3) & 1)) * 128;
    } else {
      tm = (long)blockIdx.y * 128; tn = (long)blockIdx.x * 128;
    }
  }
  const int ba = b / bdivA_;
  const int Klen = Kv / ksplit;
  const int k0 = kc * Klen;
  const u16* Ab = Ap_ + (long)ba * sA_ + aoff_;
  const u16* Bb = Bp_ + (long)b * sB_;
  const int tid = threadIdx.x;
  const int lane = tid & 63, wv = tid >> 6;
  const int wm = (wv >> 1) * 64, wn = (wv & 1) * 64;
  const int q = lane >> 4, r = lane & 15;
  const int ldr = lane >> 2;        // row within 16-row group
  const int ldc = (lane & 3) * 8;   // u16 offset within row (16B per lane)

  // global srcs for this wave's staging chunks (2 x 16 rows for A and B)
  const u16* gA0 = Ab + (tm + wv * 32 + ldr) * (long)lda_ + k0 + ldc;
  const u16* gA1 = gA0 + 16 * (long)lda_;
  const u16* gB0 = Bb + (tn + wv * 32 + ldr) * (long)ldb_ + k0 + ldc;
  const u16* gB1 = gB0 + 16 * (long)ldb_;
  const int dof = (wv * 32 + ldr) * 32 + ldc;  // LDS u16 offset within buffer

  const f32x4 zero4 = {0.0f, 0.0f, 0.0f, 0.0f};
  f32x4 acc[4][4];
#pragma unroll
  for (int i = 0; i < 4; ++i)
#pragma unroll
    for (int j = 0; j < 4; ++j) acc[i][j] = zero4;

  // prime tile 0 into registers
  uint4 ra0 = *(const uint4*)gA0;
  uint4 ra1 = *(const uint4*)gA1;
  uint4 rb0 = *(const uint4*)gB0;
  uint4 rb1 = *(const uint4*)gB1;

  const int iters = Klen >> 5;
  int cur = 0;
  for (int it = 0; it < iters; ++it) {
    // write tile 'it' into buf[cur] (other waves may still be doing MFMA on
    // buf[cur^1]; last reads of buf[cur] were before the previous barrier)
    u16* a0 = As[cur] + dof;
    u16* b0 = Bs[cur] + dof;
    *(uint4*)a0 = ra0; *(uint4*)(a0 + 512) = ra1;
    *(uint4*)b0 = rb0; *(uint4*)(b0 + 512) = rb1;
    if (it + 1 < iters) {            // prefetch tile k+1 (lands under MFMA below)
      const long o = (long)(it + 1) * 32;
      ra0 = *(const uint4*)(gA0 + o);
      ra1 = *(const uint4*)(gA1 + o);
      rb0 = *(const uint4*)(gB0 + o);
      rb1 = *(const uint4*)(gB1 + o);
    }
    __syncthreads();                 // lgkm drain: tile 'it' visible to all
    bf16x8 af[4], bfr[4];
#pragma unroll
    for (int i = 0; i < 4; ++i) {
      af[i]  = *(const bf16x8*)(As[cur] + (wm + i * 16 + r) * 32 + q * 8);
      bfr[i] = *(const bf16x8*)(Bs[cur] + (wn + i * 16 + r) * 32 + q * 8);
    }
#pragma unroll
    for (int i = 0; i < 4; ++i)
#pragma unroll
      for (int j = 0; j < 4; ++j)
        acc[i][j] = __builtin_amdgcn_mfma_f32_16x16x32_bf16(af[i], bfr[j], acc[i][j], 0, 0, 0);
    cur ^= 1;
  }

  // epilogue: D layout col=lane&15, row=(lane>>4)*4+reg  [measured m89/m91]
  const float* biasb = bias_ ? bias_ + (long)ba * sBias_ : nullptr;
#pragma unroll
  for (int i = 0; i < 4; ++i)
#pragma unroll
    for (int j = 0; j < 4; ++j)
#pragma unroll
      for (int v = 0; v < 4; ++v) {
        long row = tm + wm + i * 16 + q * 4 + v;
        long col = tn + wn + j * 16 + r;
        float val = acc[i][j][v] * al;
        if (BIAS_MODE == 1 && kc == 0) val += biasb[col];
        if (BIAS_MODE == 2 && kc == 0) val += biasb[row];
        if (RELU) val = fmaxf(val, 0.0f);
        long idx = (long)kc * sSlab + (long)b * sC_ + row * (long)Nv + col;
        if (OUT_MODE == 0)      ((float*)Cp)[idx] = val;
        else if (OUT_MODE == 1) ((u16*)Cp)[idx] = f2bf(val);
        else                    ((_Float16*)Cp)[idx] = (_Float16)val;
      }
}

// -------- blended = TT*softmax(mixed) + (1-TT)*softmax(att), rows of T1 --------
// each thread owns 8 contiguous f16 (16B vector loads/stores)
__global__ __launch_bounds__(256) void blend_softmax(
    const _Float16* __restrict__ att, const _Float16* __restrict__ mixed,
    u16* __restrict__ out)
{
  const long row = blockIdx.x;
  const int tid = threadIdx.x;
  f16x8 av = *(const f16x8*)(att + row * T1c + tid * 8);
  f16x8 mv = *(const f16x8*)(mixed + row * T1c + tid * 8);
  float a[8], m[8];
#pragma unroll
  for (int i = 0; i < 8; ++i) { a[i] = (float)av[i]; m[i] = (float)mv[i]; }
  float amax = a[0], mmax = m[0];
#pragma unroll
  for (int i = 1; i < 8; ++i) { amax = fmaxf(amax, a[i]); mmax = fmaxf(mmax, m[i]); }
#pragma unroll
  for (int off = 32; off > 0; off >>= 1) {
    amax = fmaxf(amax, __shfl_xor(amax, off));
    mmax = fmaxf(mmax, __shfl_xor(mmax, off));
  }
  __shared__ float red[8];
  const int lane = tid & 63, wv = tid >> 6;
  if (lane == 0) { red[wv] = amax; red[4 + wv] = mmax; }
  __syncthreads();
  amax = fmaxf(fmaxf(red[0], red[1]), fmaxf(red[2], red[3]));
  mmax = fmaxf(fmaxf(red[4], red[5]), fmaxf(red[6], red[7]));
  __syncthreads();
  float asum = 0.f, msum = 0.f;
#pragma unroll
  for (int i = 0; i < 8; ++i) {
    a[i] = __expf(a[i] - amax); asum += a[i];
    m[i] = __expf(m[i] - mmax); msum += m[i];
  }
#pragma unroll
  for (int off = 32; off > 0; off >>= 1) {
    asum += __shfl_xor(asum, off);
    msum += __shfl_xor(msum, off);
  }
  if (lane == 0) { red[wv] = asum; red[4 + wv] = msum; }
  __syncthreads();
  asum = red[0] + red[1] + red[2] + red[3];
  msum = red[4] + red[5] + red[6] + red[7];
  const float ca = (1.0f - TTc) / asum, cm = TTc / msum;
  u16 o[8];
#pragma unroll
  for (int i = 0; i < 8; ++i) o[i] = f2bf(a[i] * ca + m[i] * cm);
  *(uint4*)(out + row * T1c + tid * 8) = *(uint4*)o;
}

// -------- x = LN(xin + sum of 4 split-K slabs) ; writes fp32 x and bf16 x --------
__global__ __launch_bounds__(384) void add_ln4(
    const float* __restrict__ xin, const float* __restrict__ zs,
    const float* __restrict__ g, const float* __restrict__ be,
    float* __restrict__ xout, u16* __restrict__ xbf)
{
  const long row = blockIdx.x;
  const int d = threadIdx.x;
  const long SL = (long)Bc * Tc * Dc;
  const long o = row * Dc + d;
  float v = xin[o] + zs[o] + zs[SL + o] + zs[2 * SL + o] + zs[3 * SL + o];
  float s = v, s2 = v * v;
#pragma unroll
  for (int off = 32; off > 0; off >>= 1) {
    s  += __shfl_xor(s, off);
    s2 += __shfl_xor(s2, off);
  }
  __shared__ float red[12];
  const int lane = d & 63, wv = d >> 6;
  if (lane == 0) { red[wv] = s; red[6 + wv] = s2; }
  __syncthreads();
  float S = 0.f, S2 = 0.f;
#pragma unroll
  for (int w = 0; w < 6; ++w) { S += red[w]; S2 += red[6 + w]; }
  const float mean = S * (1.0f / Dc);
  const float var  = S2 * (1.0f / Dc) - mean * mean;
  const float rstd = rsqrtf(var + EPSc);
  const float y = (v - mean) * rstd * g[d] + be[d];
  xout[o] = y;
  xbf[o] = f2bf(y);
}

extern "C" void kernel_launch(void* const* d_in, const int* in_sizes, int n_in,
                              void* d_out, int out_size, void* d_ws, size_t ws_size,
                              hipStream_t stream)
{
  const float* tgt     = (const float*)d_in[0];
  const float* memory  = (const float*)d_in[1];
  const float* score_c = (const float*)d_in[2];
  const float* out_c   = (const float*)d_in[3];
  const float* Wq  = (const float*)d_in[4];  const float* bq  = (const float*)d_in[5];
  const float* Wk  = (const float*)d_in[6];  const float* bk  = (const float*)d_in[7];
  const float* Wv  = (const float*)d_in[8];  const float* bv  = (const float*)d_in[9];
  const float* Wkn = (const float*)d_in[10]; const float* bkn = (const float*)d_in[11];
  const float* Wun = (const float*)d_in[12]; const float* bun = (const float*)d_in[13];
  const float* W1  = (const float*)d_in[14]; const float* b1  = (const float*)d_in[15];
  const float* W2  = (const float*)d_in[16]; const float* b2  = (const float*)d_in[17];
  const float* g1  = (const float*)d_in[18]; const float* be1 = (const float*)d_in[19];
  const float* g2  = (const float*)d_in[20]; const float* be2 = (const float*)d_in[21];
  (void)bk; (void)in_sizes; (void)n_in; (void)out_size;

  char* p = (char*)d_ws;
  auto alloc = [&](size_t b) { char* r = p; p += (b + 255) & ~(size_t)255; return r; };

  u16* wv_bf   = (u16*)alloc((size_t)Lc * Dc * DKc * 2);
  u16* wkn_bf  = (u16*)alloc((size_t)Lc * Dc * Dc * 2);
  u16* w1_bf   = (u16*)alloc((size_t)Lc * FFc * Dc * 2);
  u16* w2_bf   = (u16*)alloc((size_t)Lc * Dc * FFc * 2);
  u16* wqT     = (u16*)alloc((size_t)Lc * Dc * Dc * 2);      // [l][384][384] Wq^T
  u16* wkT     = (u16*)alloc((size_t)Lc * DKc * Dc * 2);     // [l][256][384] Wk^T
  u16* wqu_bf  = (u16*)alloc((size_t)Lc * QUc * Dc * 2);     // [l][640][384] = [WqkT; Wun]
  float* bqu   = (float*)alloc((size_t)Lc * QUc * 4);
  u16* mem_bf  = (u16*)alloc((size_t)Bc * T1c * DKc * 2);
  u16* outc_bf = (u16*)alloc((size_t)Lc * Bc * TCc * Dc * 2);
  u16* x_bf    = (u16*)alloc((size_t)Bc * Tc * Dc * 2);
  float* xbuf  = (float*)alloc((size_t)Bc * Tc * Dc * 4);
  u16* qunk_bf = (u16*)alloc((size_t)Bc * Tc * QUc * 2);      // [B*T][640]
  u16* vT_all  = (u16*)alloc((size_t)Bc * Lc * Dc * T1c * 2); // [b][1536][2048]
  u16* knoT_all = (u16*)alloc((size_t)Lc * Bc * Dc * TCc * 2); // [l][b][384][1024]
  u16* M2T_all = (u16*)alloc((size_t)Lc * Bc * T1c * Dc * 2);  // [l][b][2048][384]
  u16* scT_all = (u16*)alloc((size_t)Lc * Bc * T1c * TCc * 2);
  _Float16* att   = (_Float16*)alloc((size_t)Bc * Tc * T1c * 2);
  _Float16* mixed = (_Float16*)alloc((size_t)Bc * Tc * T1c * 2);
  u16* blended = (u16*)alloc((size_t)Bc * Tc * T1c * 2);
  float* zslab = (float*)alloc((size_t)4 * Bc * Tc * Dc * 4);
  float* yslab = (float*)alloc((size_t)4 * Bc * Tc * Dc * 4);
  u16* h_bf    = (u16*)alloc((size_t)Bc * Tc * FFc * 2);

  if ((size_t)(p - (char*)d_ws) > ws_size) return;  // fail loudly (poisoned out)

  // ---- single multi-convert launch ----
  {
    CPack cp{}; int g = 0; long tot4 = 0;
    auto add = [&](const float* s, u16* d, long n) {
      cp.d[g].src = s; cp.d[g].dst = d; cp.d[g].n4 = n / 4; tot4 += n / 4; ++g;
    };
    add(Wv,  wv_bf,  (long)Lc * Dc * DKc);
    add(Wkn, wkn_bf, (long)Lc * Dc * Dc);
    add(W1,  w1_bf,  (long)Lc * FFc * Dc);
    add(W2,  w2_bf,  (long)Lc * Dc * FFc);
    add(memory, mem_bf, (long)Bc * T1c * DKc);
    add(out_c, outc_bf, (long)Lc * Bc * TCc * Dc);
    add(tgt, x_bf, (long)Bc * Tc * Dc);
    for (int l = 0; l < Lc; ++l)  // Wun -> wqu rows [256..640)
      add(Wun + (long)l * Dc * Dc,
          wqu_bf + (long)l * QUc * Dc + (long)DKc * Dc, (long)Dc * Dc);
    cp.nd = g; cp.tot4 = tot4;
    cvt_multi<<<4096, 256, 0, stream>>>(cp);
  }

  // score_c transpose (1024x2048 -> 2048x1024) x16
  transpose_cvt<<<dim3(T1c / 64, TCc / 64, Lc * Bc), 256, 0, stream>>>(
      score_c, scT_all, TCc, T1c, nullptr, nullptr, 0, Lc * Bc);
  // fused Wq (384x384) + Wk (384x256) transposes in one launch (z<Lc: Wq)
  transpose_cvt<<<dim3(Dc / 64, Dc / 64, 2 * Lc), 256, 0, stream>>>(
      Wq, wqT, Dc, Dc, Wk, wkT, DKc, Lc);

  const float scale = 1.0f / sqrtf((float)Dc);
  const long SLAB = (long)Bc * Tc * Dc;

  // WqkT[l] = WkT[l] . WqT[l]^T  (256 x 384, K=384) -> wqu rows [0..256)
  gemm_bt<0,0,1,0,0><<<dim3(Dc/128, DKc/128, Lc), 256, 0, stream>>>(
      wkT, wqT, wqu_bf, nullptr, 1.0f, Dc, Dc, Dc, Dc,
      (long)DKc*Dc, (long)Dc*Dc, (long)QUc*Dc, 0, 1, 0, 1,
      nullptr, 0, 0, 0, nullptr, 0.f, 0, Dc,
      nullptr, 0, 0, nullptr, 0, 1, 0, 0, 0, 0, 0, 0, 0);
  // bqu[l] = [bq.Wk ; bun]
  make_bias<<<Lc, QUc, 0, stream>>>(bq, bun, wkT, bqu);

  // FUSED (DUAL=2): vT_all[b] = Wv_all . memory[b]^T + bv(row)  (1536x2048,K=256) x4
  //            AND  knoT_all[l][b] = Wkn[l] . out_c[l][b]^T + bkn[l](row) (384x1024,K=384) x16
  gemm_bt<2,0,1,0,2><<<dim3(768 + 384, 1, 1), 256, 0, stream>>>(
      wv_bf, mem_bf, vT_all, bv, 1.0f, T1c, DKc, DKc, DKc,
      0, (long)T1c*DKc, (long)Lc*Dc*T1c, 0, 1, 0, 1,
      outc_bf, Dc, (long)TCc*Dc, 0, knoT_all, 1.0f, 0, Dc,
      wkn_bf, Dc, (long)Dc*Dc, bkn, Dc, Bc,
      TCc, (long)Dc*TCc, 768, 16, 12, 8, 3);
  // M2T_all[l][b] = scale * scT[l][b] . knoT[l][b]^T  (2048 x 384, K=1024) x16
  gemm_bt<0,0,1,0,0><<<dim3(Dc/128, T1c/128, Lc*Bc), 256, 0, stream>>>(
      scT_all, knoT_all, M2T_all, nullptr, scale, Dc, TCc, TCc, TCc,
      (long)T1c*TCc, (long)Dc*TCc, (long)T1c*Dc, 0, 1, 0, 1,
      nullptr, 0, 0, 0, nullptr, 0.f, 0, TCc,
      nullptr, 0, 0, nullptr, 0, 1, 0, 0, 0, 0, 0, 0, 0);

  for (int l = 0; l < Lc; ++l) {
    // qunk = x . [WqkT;Wun]^T + [bq.Wk;bun]   (4096 x 640, K=384)
    gemm_bt<1,0,1,0,0><<<dim3(QUc/128, Bc*Tc/128, 1), 256, 0, stream>>>(
        x_bf, wqu_bf + (long)l*QUc*Dc, qunk_bf, bqu + l*QUc,
        1.0f, QUc, Dc, Dc, Dc, 0, 0, 0, 0, 1, 0, 1,
        nullptr, 0, 0, 0, nullptr, 0.f, 0, Dc,
        nullptr, 0, 0, nullptr, 0, 1, 0, 0, 0, 0, 0, 0, 0);
    // DUAL: att[b] = scale * qk[b].mem[b]^T (K=256)   [bk dropped: softmax
    //       row-shift invariance]  AND  mixed[b] = unk[b].M2T[l][b]^T (K=384)
    gemm_bt<0,0,2,1,1><<<dim3(T1c/128, Tc/128, 2*Bc), 256, 0, stream>>>(
        qunk_bf, mem_bf, att, nullptr, scale, T1c, DKc, QUc, DKc,
        (long)Tc*QUc, (long)T1c*DKc, (long)Tc*T1c, 0, 1, 0, 1,
        M2T_all + (long)l*Bc*T1c*Dc, Dc, (long)T1c*Dc, DKc, mixed, 1.0f, Bc, Dc,
        nullptr, 0, 0, nullptr, 0, 1, 0, 0, 0, 0, 0, 0, 0);
    // blended = TT*softmax(mixed) + (1-TT)*softmax(att)
    blend_softmax<<<Bc*Tc, 256, 0, stream>>>(att, mixed, blended);
    // z[b] = blended[b] . vT[l][b]^T   (1024 x 384, K=2048), split-K=4 slabs
    gemm_bt<0,0,0,0,0><<<dim3(Dc/128, Tc/128, Bc*4), 256, 0, stream>>>(
        blended, vT_all + (long)l*Dc*T1c, zslab, nullptr, 1.0f,
        Dc, T1c, T1c, T1c, (long)Tc*T1c, (long)Lc*Dc*T1c, (long)Tc*Dc, 0, 4, SLAB, 1,
        nullptr, 0, 0, 0, nullptr, 0.f, 0, T1c,
        nullptr, 0, 0, nullptr, 0, 1, 0, 0, 0, 0, 0, 0, 0);
    // x = LN(x + sum(zslab))
    add_ln4<<<Bc*Tc, Dc, 0, stream>>>(
        (l == 0) ? tgt : xbuf, zslab, g1 + l*Dc, be1 + l*Dc, xbuf, x_bf);
    // h = relu(x . W1^T + b1)   (4096 x 1536, K=384) bf16
    gemm_bt<1,1,1,0,0><<<dim3(FFc/128, Bc*Tc/128, 1), 256, 0, stream>>>(
        x_bf, w1_bf + (long)l*FFc*Dc, h_bf, b1 + l*FFc, 1.0f,
        FFc, Dc, Dc, Dc, 0, 0, 0, 0, 1, 0, 1,
        nullptr, 0, 0, 0, nullptr, 0.f, 0, Dc,
        nullptr, 0, 0, nullptr, 0, 1, 0, 0, 0, 0, 0, 0, 0);
    // y2 = h . W2^T + b2   (4096 x 384, K=1536), split-K=4 slabs
    gemm_bt<1,0,0,0,0><<<dim3(Dc/128, Bc*Tc/128, 4), 256, 0, stream>>>(
        h_bf, w2_bf + (long)l*Dc*FFc, yslab, b2 + l*Dc, 1.0f,
        Dc, FFc, FFc, FFc, 0, 0, 0, 0, 4, SLAB, 1,
        nullptr, 0, 0, 0, nullptr, 0.f, 0, FFc,
        nullptr, 0, 0, nullptr, 0, 1, 0, 0, 0, 0, 0, 0, 0);
    // x = LN(x + sum(yslab)) ; last layer writes d_out
    add_ln4<<<Bc*Tc, Dc, 0, stream>>>(
        xbuf, yslab, g2 + l*Dc, be2 + l*Dc,
        (l == Lc - 1) ? (float*)d_out : xbuf, x_bf);
  }
}